// Round 10
// baseline (242.219 us; speedup 1.0000x reference)
//
#include <hip/hip_runtime.h>
#include <hip/hip_bf16.h>
#include <math.h>

typedef unsigned short u16;
typedef __attribute__((ext_vector_type(8))) short s16x8;
typedef __attribute__((ext_vector_type(4))) float f32x4;
typedef __attribute__((ext_vector_type(16))) float f32x16;

#define B_ 4
#define N_ 4096
#define C_ 1024
#define M_ (B_*N_)
#define NT_ 16   // K / 64

__device__ __forceinline__ u16 f2bf(float f) {
  unsigned u = __builtin_bit_cast(unsigned, f);
  u = u + 0x7fffu + ((u >> 16) & 1u);
  return (u16)(u >> 16);
}
__device__ __forceinline__ float bf2f(u16 h) {
  unsigned u = ((unsigned)h) << 16;
  return __builtin_bit_cast(float, u);
}

// ---------------- kernel T: one-time rope trig table (512 pairs) ----------------
__global__ void trig_kernel(float* __restrict__ ctab, float* __restrict__ stab) {
  const int i = threadIdx.x;   // 0..511
  const float theta = powf(10000.f, -(float)i * (1.f/512.f));
  ctab[i] = cosf(theta);
  stab[i] = sinf(theta);
}

// ---------------- kernel 0: fp32 -> bf16 precast of x and W ----------------
__global__ __launch_bounds__(256) void cast_kernel(
    const float* __restrict__ x, const float* __restrict__ w,
    u16* __restrict__ xb, u16* __restrict__ wb)
{
  const int NX4 = M_*C_/4;     // 4194304
  const int NW4 = 2048*C_/4;   // 524288
  int tid = blockIdx.x*256 + threadIdx.x;
  int stride = gridDim.x*256;
  for (int i = tid; i < NX4; i += stride) {
    f32x4 v = ((const f32x4*)x)[i];
    ushort4 o;
    o.x = f2bf(v[0]); o.y = f2bf(v[1]); o.z = f2bf(v[2]); o.w = f2bf(v[3]);
    ((ushort4*)xb)[i] = o;
  }
  for (int i = tid; i < NW4; i += stride) {
    f32x4 v = ((const f32x4*)w)[i];
    ushort4 o;
    o.x = f2bf(v[0]); o.y = f2bf(v[1]); o.z = f2bf(v[2]); o.w = f2bf(v[3]);
    ((ushort4*)wb)[i] = o;
  }
}

// ---------------- kernel 1: qk GEMM (32x32x16 MFMA) + bias + elu+1 + ROPE ----
// 256x256 tile, BK=64, 8 waves (2M x 4N), per-wave 128x64 = 4mf x 2nf of 32x32.
// LDS: A ring-3 (96KB) + B single (32KB). 2 barriers/kt (32 total). Counted
// vmcnt(4)/kt: FIFO [A(kt+1), B(kt+1), A(kt+2)] -> drain first 8, keep A(kt+2).
__global__ __launch_bounds__(512, 2) void gemm_kernel(
    const u16* __restrict__ xb, const u16* __restrict__ wb,
    const float* __restrict__ bqk,
    const float* __restrict__ ctab, const float* __restrict__ stab,
    u16* __restrict__ qrb, u16* __restrict__ krb)
{
  __shared__ __align__(16) unsigned char As[3][32768];  // ring-3: 256r x 128B
  __shared__ __align__(16) unsigned char Bs[32768];     // single: 256n x 128B
  const int t = threadIdx.x;             // 0..511
  const int l = t & 63;
  const int w = t >> 6;                  // 0..7
  const int wm = w >> 2, wn = w & 3;     // 2M x 4N
  const int m0 = blockIdx.x * 256;
  const int n0 = blockIdx.y * 256;

  f32x16 acc[4][2];
  #pragma unroll
  for (int a = 0; a < 4; ++a)
    #pragma unroll
    for (int b = 0; b < 2; ++b)
      #pragma unroll
      for (int r = 0; r < 16; ++r) acc[a][b][r] = 0.f;

  // staging: thread t stages rows (t>>3)+{0,64,128,192}, chunk (t&7), pre-swizzled
  const int s_cole = ((t & 7) ^ ((t >> 3) & 7)) << 3;      // element offset 0..56
  const size_t a_base = (size_t)(m0 + (t >> 3)) * 1024 + s_cole;
  const size_t b_base = (size_t)(n0 + (t >> 3)) * 1024 + s_cole;

  #define GLA(slot, kt) do {                                                   \
    _Pragma("unroll")                                                          \
    for (int i_ = 0; i_ < 4; ++i_)                                             \
      __builtin_amdgcn_global_load_lds(                                        \
        (const __attribute__((address_space(1))) void*)(xb + a_base + (size_t)i_*65536 + (kt)*64), \
        (__attribute__((address_space(3))) void*)(&As[slot][(i_*512 + w*64)*16]), 16, 0, 0); \
  } while (0)
  #define GLB(kt) do {                                                         \
    _Pragma("unroll")                                                          \
    for (int i_ = 0; i_ < 4; ++i_)                                             \
      __builtin_amdgcn_global_load_lds(                                        \
        (const __attribute__((address_space(1))) void*)(wb + b_base + (size_t)i_*65536 + (kt)*64), \
        (__attribute__((address_space(3))) void*)(&Bs[(i_*512 + w*64)*16]), 16, 0, 0); \
  } while (0)

  // prologue: A(0)->slot0, B(0), A(1)->slot1; drain A0+B0, keep A1 in flight
  GLA(0, 0); GLB(0); GLA(1, 1);
  asm volatile("s_waitcnt vmcnt(4)" ::: "memory");
  __builtin_amdgcn_s_barrier();

  const int kq = (l >> 5) * 16;          // k-byte sub-offset within frag
  for (int kt = 0; kt < NT_; ++kt) {
    const unsigned char* Ab = As[kt % 3];

    // ---- phase 0: B-frags + A-frags mf0,1; MFMA mf0,1 ----
    s16x8 bfr[2][4], af[2][4];
    #pragma unroll
    for (int nf = 0; nf < 2; ++nf) {
      const int r = wn*64 + nf*32 + (l & 31);
      #pragma unroll
      for (int ks = 0; ks < 4; ++ks)
        bfr[nf][ks] = *(const s16x8*)(Bs + r*128 + ((ks*32 + kq) ^ ((r & 7) << 4)));
    }
    #pragma unroll
    for (int mf = 0; mf < 2; ++mf) {
      const int r = wm*128 + mf*32 + (l & 31);
      #pragma unroll
      for (int ks = 0; ks < 4; ++ks)
        af[mf][ks] = *(const s16x8*)(Ab + r*128 + ((ks*32 + kq) ^ ((r & 7) << 4)));
    }
    __builtin_amdgcn_s_setprio(1);
    #pragma unroll
    for (int mf = 0; mf < 2; ++mf)
      #pragma unroll
      for (int nf = 0; nf < 2; ++nf)
        #pragma unroll
        for (int ks = 0; ks < 4; ++ks)
          acc[mf][nf] = __builtin_amdgcn_mfma_f32_32x32x16_bf16(
              af[mf][ks], bfr[nf][ks], acc[mf][nf], 0, 0, 0);
    __builtin_amdgcn_s_setprio(0);
    // all waves' B ds_reads complete before any wave overwrites Bs
    __builtin_amdgcn_s_barrier();

    // ---- phase 1: stage kt+1 B (single slot) + kt+2 A (ring); MFMA mf2,3 ----
    if (kt + 1 < NT_) GLB(kt + 1);
    if (kt + 2 < NT_) GLA((kt + 2) % 3, kt + 2);
    s16x8 af2[2][4];
    #pragma unroll
    for (int mf = 0; mf < 2; ++mf) {
      const int r = wm*128 + (mf + 2)*32 + (l & 31);
      #pragma unroll
      for (int ks = 0; ks < 4; ++ks)
        af2[mf][ks] = *(const s16x8*)(Ab + r*128 + ((ks*32 + kq) ^ ((r & 7) << 4)));
    }
    __builtin_amdgcn_s_setprio(1);
    #pragma unroll
    for (int mf = 0; mf < 2; ++mf)
      #pragma unroll
      for (int nf = 0; nf < 2; ++nf)
        #pragma unroll
        for (int ks = 0; ks < 4; ++ks)
          acc[mf + 2][nf] = __builtin_amdgcn_mfma_f32_32x32x16_bf16(
              af2[mf][ks], bfr[nf][ks], acc[mf + 2][nf], 0, 0, 0);
    __builtin_amdgcn_s_setprio(0);
    // counted drain: FIFO = [A(kt+1), B(kt+1), A(kt+2)] -> drain 8, keep 4
    if (kt + 2 < NT_)      asm volatile("s_waitcnt vmcnt(4)" ::: "memory");
    else if (kt + 1 < NT_) asm volatile("s_waitcnt vmcnt(0)" ::: "memory");
    __builtin_amdgcn_s_barrier();
  }
  #undef GLA
  #undef GLB

  // epilogue (32x32 C layout: col=lane&31, row=(r&3)+8*(r>>2)+4*(lane>>5))
  #pragma unroll
  for (int nf = 0; nf < 2; ++nf) {
    const int col = n0 + wn*64 + nf*32 + (l & 31);   // 0..2047
    const float bias = bqk[col];
    const int cc = col & 1023;
    const float cn = ctab[cc >> 1];
    const float sn = stab[cc >> 1];
    u16* dst = (col < 1024) ? qrb : krb;
    #pragma unroll
    for (int mf = 0; mf < 4; ++mf) {
      #pragma unroll
      for (int r = 0; r < 16; ++r) {
        const int rowm = m0 + wm*128 + mf*32 + (r & 3) + 8*(r >> 2) + 4*(l >> 5);
        float v = acc[mf][nf][r] + bias;
        v = (v > 0.f) ? (v + 1.f) : __expf(v);      // elu(v)+1
        const float vp = __shfl_xor(v, 1);          // partner column (elu'd)
        const float vr = (col & 1) ? (sn*vp + cn*v) : (cn*v - sn*vp);
        dst[(size_t)rowm*1024 + cc] = f2bf(vr);
      }
    }
  }
}

// ---------------- kernel 2: kv partials: 8d x 8e per thread, 16 n-slices ----------
__global__ __launch_bounds__(256, 4) void kvpart_kernel(
    const u16* __restrict__ krb, const u16* __restrict__ xb,
    float* __restrict__ partial, float* __restrict__ kmr)
{
  __shared__ float red[2][64][65];   // odd stride: conflict-free lane columns
  const int t = threadIdx.x;
  const int l = t & 63;
  const int nsub = t >> 6;
  const int dg = l >> 3, eg = l & 7;
  const int d0 = dg*8, e0 = eg*8;
  const int blk = blockIdx.x;
  const int bh = blk >> 4;
  const int ns = blk & 15;
  const int b = bh >> 4, h = bh & 15;

  float acc[8][8];
  #pragma unroll
  for (int i=0;i<8;++i)
    #pragma unroll
    for (int j=0;j<8;++j) acc[i][j]=0.f;
  float ksum[8];
  #pragma unroll
  for (int i=0;i<8;++i) ksum[i]=0.f;

  const size_t base = ((size_t)b*4096 + ns*256 + nsub*64) * 1024 + h*64;
  #pragma unroll 2
  for (int it = 0; it < 64; ++it) {
    const size_t roff = base + (size_t)it*1024;
    const s16x8 k8 = *(const s16x8*)(krb + roff + d0);
    const s16x8 v8 = *(const s16x8*)(xb + roff + e0);
    float kf[8], vf[8];
    #pragma unroll
    for (int i=0;i<8;++i){ kf[i]=bf2f((u16)k8[i]); vf[i]=bf2f((u16)v8[i]); }
    #pragma unroll
    for (int i=0;i<8;++i){
      ksum[i]+=kf[i];
      #pragma unroll
      for (int j=0;j<8;++j) acc[i][j] += kf[i]*vf[j];
    }
  }

  if (nsub >= 2) {
    #pragma unroll
    for (int i=0;i<8;++i)
      #pragma unroll
      for (int j=0;j<8;++j) red[nsub-2][l][i*8+j] = acc[i][j];
  }
  __syncthreads();
  if (nsub < 2) {
    #pragma unroll
    for (int i=0;i<8;++i)
      #pragma unroll
      for (int j=0;j<8;++j) acc[i][j] += red[nsub][l][i*8+j];
  }
  __syncthreads();
  if (nsub == 1) {
    #pragma unroll
    for (int i=0;i<8;++i)
      #pragma unroll
      for (int j=0;j<8;++j) red[0][l][i*8+j] = acc[i][j];
  }
  __syncthreads();
  if (nsub == 0) {
    float* dst = partial + ((size_t)ns*64 + bh)*4096 + d0*64 + e0;
    #pragma unroll
    for (int i=0;i<8;++i) {
      f32x4 lo, hi;
      #pragma unroll
      for (int j=0;j<4;++j) { lo[j] = acc[i][j] + red[0][l][i*8+j];
                              hi[j] = acc[i][j+4] + red[0][l][i*8+j+4]; }
      *(f32x4*)(dst + i*64)     = lo;
      *(f32x4*)(dst + i*64 + 4) = hi;
    }
  }
  if (eg == 0) {
    #pragma unroll
    for (int i=0;i<8;++i)
      atomicAdd(kmr + bh*64 + d0 + i, ksum[i] * (1.f/4096.f));
  }
}

// ---------------- kernel 2b: sum 16 partial slices, *1/n, transpose -> kvbT bf16 ----
__global__ __launch_bounds__(256) void kvred_kernel(
    const float* __restrict__ partial, u16* __restrict__ kvbT)
{
  __shared__ float s[4096];
  const int bh = blockIdx.x;
  const int t = threadIdx.x;
  f32x4 a0={0,0,0,0}, a1={0,0,0,0}, a2={0,0,0,0}, a3={0,0,0,0};
  #pragma unroll
  for (int sl=0; sl<16; ++sl) {
    const f32x4* p = (const f32x4*)(partial + ((size_t)sl*64 + bh)*4096 + t*16);
    a0 += p[0]; a1 += p[1]; a2 += p[2]; a3 += p[3];
  }
  ((f32x4*)s)[t*4+0]=a0; ((f32x4*)s)[t*4+1]=a1;
  ((f32x4*)s)[t*4+2]=a2; ((f32x4*)s)[t*4+3]=a3;
  __syncthreads();
  const float inv_n = 1.f / 4096.f;
  s16x8 o0, o1;
  #pragma unroll
  for (int j=0;j<8;++j) {
    o0[j] = (short)f2bf(s[((t&3)*16 + j)*64 + (t>>2)] * inv_n);
    o1[j] = (short)f2bf(s[((t&3)*16 + 8 + j)*64 + (t>>2)] * inv_n);
  }
  *(s16x8*)(kvbT + (size_t)bh*4096 + t*16) = o0;
  *(s16x8*)(kvbT + (size_t)bh*4096 + t*16 + 8) = o1;
}

// ---------------- kernel 3: attn MFMA + fused z + z scale + fused pe conv ----------
__global__ __launch_bounds__(256) void attn_kernel(
    const u16* __restrict__ qrb, const u16* __restrict__ kvbT,
    const float* __restrict__ kmr, const float* __restrict__ x,
    const float* __restrict__ lw, const float* __restrict__ lb,
    float* __restrict__ out)
{
  __shared__ __align__(16) unsigned char As[16384]; // 128 rows x 128B
  __shared__ __align__(16) unsigned char Bs[8192];  // 64 rows x 128B
  __shared__ float lws[192], lbs[64];
  __shared__ float kms[64];
  __shared__ float zs[128];
  const int t = threadIdx.x, l = t & 63, w = t >> 6;
  const int m0 = blockIdx.x * 128;
  const int h = blockIdx.y, b = blockIdx.z;
  const size_t qbase = ((size_t)b*4096 + m0) * 1024 + h*64;
  const u16* kvsrc = kvbT + ((size_t)(b*16 + h) << 12);

  #pragma unroll
  for (int i = 0; i < 4; ++i) {
    const int jc   = i*256 + t;
    const int row  = jc >> 3;                          // 0..127
    const int cole = (((jc & 7) << 4) ^ ((row & 7) << 4)) >> 1;
    const int ldsoff = (i*256 + w*64) * 16;
    __builtin_amdgcn_global_load_lds(
      (const __attribute__((address_space(1))) void*)(qrb + qbase + (size_t)row*1024 + cole),
      (__attribute__((address_space(3))) void*)(As + ldsoff), 16, 0, 0);
  }
  #pragma unroll
  for (int i = 0; i < 2; ++i) {
    const int jc   = i*256 + t;
    const int row  = jc >> 3;                          // e: 0..63
    const int cole = (((jc & 7) << 4) ^ ((row & 7) << 4)) >> 1;
    const int ldsoff = (i*256 + w*64) * 16;
    __builtin_amdgcn_global_load_lds(
      (const __attribute__((address_space(1))) void*)(kvsrc + (size_t)row*64 + cole),
      (__attribute__((address_space(3))) void*)(Bs + ldsoff), 16, 0, 0);
  }
  if (t < 192) lws[t] = lw[h*192 + t];
  if (t >= 192)  lbs[t-192] = lb[h*64 + (t-192)];
  if (t < 64) kms[t] = kmr[(b*16 + h)*64 + t];
  __syncthreads();

  // fused z: row r = t>>1, d-half = t&1; q from swizzled As
  {
    const int r = t >> 1, half = t & 1;
    const int swz = (r & 7) << 4;
    float zp = 0.f;
    #pragma unroll
    for (int c = 0; c < 4; ++c) {
      const int kb = half*64 + c*16;
      const s16x8 qv = *(const s16x8*)(As + r*128 + (kb ^ swz));
      #pragma unroll
      for (int j = 0; j < 8; ++j) zp += bf2f((u16)qv[j]) * kms[half*32 + c*8 + j];
    }
    zp += __shfl_xor(zp, 1);
    if (!half) zs[r] = 1.f / (zp + 1e-6f);
  }

  f32x4 acc[2][4];
  #pragma unroll
  for (int a = 0; a < 2; ++a)
    #pragma unroll
    for (int c = 0; c < 4; ++c) acc[a][c] = (f32x4){0.f,0.f,0.f,0.f};

  #pragma unroll
  for (int ks = 0; ks < 2; ++ks) {
    const int kbyte = ks*64 + ((l >> 4) << 4);
    s16x8 af[2], bf[4];
    #pragma unroll
    for (int mi = 0; mi < 2; ++mi) {
      const int r = w*32 + mi*16 + (l & 15);
      af[mi] = *(const s16x8*)(As + r*128 + (kbyte ^ ((r & 7) << 4)));
    }
    #pragma unroll
    for (int ni = 0; ni < 4; ++ni) {
      const int r = ni*16 + (l & 15);
      bf[ni] = *(const s16x8*)(Bs + r*128 + (kbyte ^ ((r & 7) << 4)));
    }
    #pragma unroll
    for (int mi = 0; mi < 2; ++mi)
      #pragma unroll
      for (int ni = 0; ni < 4; ++ni)
        acc[mi][ni] = __builtin_amdgcn_mfma_f32_16x16x32_bf16(af[mi], bf[ni], acc[mi][ni], 0, 0, 0);
  }
  __syncthreads();   // zs ready for epilogue

  // epilogue: out = acc * z[row] + pe(x)
  #pragma unroll
  for (int mi = 0; mi < 2; ++mi) {
    #pragma unroll
    for (int j = 0; j < 4; ++j) {
      const int rowm = m0 + w*32 + mi*16 + ((l >> 4) << 2) + j;
      const float zr = zs[rowm - m0];
      const size_t rbase = ((size_t)b*4096 + rowm)*1024;
      #pragma unroll
      for (int ni = 0; ni < 4; ++ni) {
        const int cl = ni*16 + (l & 15);       // in-head channel 0..63
        const int c = h*64 + cl;
        float pe = lbs[cl] + x[rbase + c]*lws[cl*3+1];
        if (rowm > 0)    pe += x[rbase - 1024 + c]*lws[cl*3];
        if (rowm < 4095) pe += x[rbase + 1024 + c]*lws[cl*3+2];
        out[rbase + c] = acc[mi][ni][j]*zr + pe;
      }
    }
  }
}

extern "C" void kernel_launch(void* const* d_in, const int* in_sizes, int n_in,
                              void* d_out, int out_size, void* d_ws, size_t ws_size,
                              hipStream_t stream) {
  const float* x   = (const float*)d_in[0];
  const float* Wqk = (const float*)d_in[1];
  const float* bqk = (const float*)d_in[2];
  const float* lw  = (const float*)d_in[3];
  const float* lb  = (const float*)d_in[4];
  float* out = (float*)d_out;

  char* ws = (char*)d_ws;
  u16* xb    = (u16*)(ws);                       // 33.55 MB  x bf16
  u16* qrb   = (u16*)(ws + 33554432ull);         // 33.55 MB  q_rope bf16
  u16* krb   = (u16*)(ws + 67108864ull);         // 33.55 MB  k_rope bf16
  u16* wb    = (u16*)(ws + 100663296ull);        //  4.19 MB  W bf16
  float* kmr = (float*)(ws + 104857600ull);      // 16 KB     fp32
  float* ctab= (float*)(ws + 104874368ull);      //  2 KB
  float* stab= (float*)(ws + 104876416ull);      //  2 KB
  u16* kvbT  = (u16*)(ws + 104878464ull);        // 0.5 MB    kv^T bf16
  // kv partials (16.8 MB fp32) live in d_out scratch; attn overwrites all of out later.
  float* partial = out;

  hipMemsetAsync(kmr, 0, 16384ull, stream);      // atomic target only
  hipLaunchKernelGGL(trig_kernel, dim3(1), dim3(512), 0, stream, ctab, stab);
  hipLaunchKernelGGL(cast_kernel, dim3(2048), dim3(256), 0, stream, x, Wqk, xb, wb);
  hipLaunchKernelGGL(gemm_kernel, dim3(64, 8), dim3(512), 0, stream, xb, wb, bqk, ctab, stab, qrb, krb);
  hipLaunchKernelGGL(kvpart_kernel, dim3(1024), dim3(256), 0, stream, krb, xb, partial, kmr);
  hipLaunchKernelGGL(kvred_kernel, dim3(64), dim3(256), 0, stream, partial, kvbT);
  hipLaunchKernelGGL(attn_kernel, dim3(32, 16, 4), dim3(256), 0, stream, qrb, kvbT, kmr, x, lw, lb, out);
}